// Round 1
// baseline (239.302 us; speedup 1.0000x reference)
//
#include <hip/hip_runtime.h>

// Causal depthwise conv1d: out[b,t,f] = sum_k w[k,f] * x[b, t-(K-1)+k, f] + bias[f]
// B=4, T=8192, F=1024, K=4. All float32. Memory-bound streaming stencil.

constexpr int Bc = 4;
constexpr int Tc = 8192;
constexpr int Fc = 1024;
constexpr int Kc = 4;
constexpr int TCHUNK = 32;                 // t-rows per block
constexpr int CHUNKS = Tc / TCHUNK;        // 256
constexpr int NBLK = Bc * CHUNKS;          // 1024 blocks

__global__ __launch_bounds__(256) void causal_conv1d_kernel(
    const float* __restrict__ x,
    const float* __restrict__ w,      // (K,1,F) -> w[k*F + f]
    const float* __restrict__ bias,   // (F,)
    float* __restrict__ out)
{
    const int f4  = threadIdx.x;      // 0..255 -> feature group of 4
    const int f   = f4 * 4;
    const int bt  = blockIdx.x;       // 0..NBLK-1
    const int b   = bt / CHUNKS;
    const int t0  = (bt % CHUNKS) * TCHUNK;

    // Per-thread taps and bias (tiny, L2/L3-resident after first block)
    const float4 w0 = *reinterpret_cast<const float4*>(w + 0 * Fc + f);
    const float4 w1 = *reinterpret_cast<const float4*>(w + 1 * Fc + f);
    const float4 w2 = *reinterpret_cast<const float4*>(w + 2 * Fc + f);
    const float4 w3 = *reinterpret_cast<const float4*>(w + 3 * Fc + f);
    const float4 bv = *reinterpret_cast<const float4*>(bias + f);

    const float* xp = x   + (size_t)b * Tc * Fc + f;
    float*       op = out + (size_t)b * Tc * Fc + f;

    // Sliding window: x[t-3], x[t-2], x[t-1]
    float4 xm3, xm2, xm1;
    if (t0 >= 3) {
        xm3 = *reinterpret_cast<const float4*>(xp + (size_t)(t0 - 3) * Fc);
        xm2 = *reinterpret_cast<const float4*>(xp + (size_t)(t0 - 2) * Fc);
        xm1 = *reinterpret_cast<const float4*>(xp + (size_t)(t0 - 1) * Fc);
    } else {
        // t0 == 0: causal zero-padding
        xm3 = make_float4(0.f, 0.f, 0.f, 0.f);
        xm2 = make_float4(0.f, 0.f, 0.f, 0.f);
        xm1 = make_float4(0.f, 0.f, 0.f, 0.f);
    }

#pragma unroll
    for (int i = 0; i < TCHUNK; ++i) {
        const int t = t0 + i;
        const float4 xc = *reinterpret_cast<const float4*>(xp + (size_t)t * Fc);

        float4 o;
        o.x = fmaf(w3.x, xc.x, fmaf(w2.x, xm1.x, fmaf(w1.x, xm2.x, fmaf(w0.x, xm3.x, bv.x))));
        o.y = fmaf(w3.y, xc.y, fmaf(w2.y, xm1.y, fmaf(w1.y, xm2.y, fmaf(w0.y, xm3.y, bv.y))));
        o.z = fmaf(w3.z, xc.z, fmaf(w2.z, xm1.z, fmaf(w1.z, xm2.z, fmaf(w0.z, xm3.z, bv.z))));
        o.w = fmaf(w3.w, xc.w, fmaf(w2.w, xm1.w, fmaf(w1.w, xm2.w, fmaf(w0.w, xm3.w, bv.w))));

        *reinterpret_cast<float4*>(op + (size_t)t * Fc) = o;

        xm3 = xm2;
        xm2 = xm1;
        xm1 = xc;
    }
}

extern "C" void kernel_launch(void* const* d_in, const int* in_sizes, int n_in,
                              void* d_out, int out_size, void* d_ws, size_t ws_size,
                              hipStream_t stream) {
    const float* x    = (const float*)d_in[0];
    const float* w    = (const float*)d_in[1];
    const float* bias = (const float*)d_in[2];
    float* out        = (float*)d_out;

    causal_conv1d_kernel<<<NBLK, 256, 0, stream>>>(x, w, bias, out);
}

// Round 2
// 233.148 us; speedup vs baseline: 1.0264x; 1.0264x over previous
//
#include <hip/hip_runtime.h>

// Causal depthwise conv1d: out[b,t,f] = sum_k w[k,f] * x[b, t-(K-1)+k, f] + bias[f]
// B=4, T=8192, F=1024, K=4. float32. Memory-bound streaming stencil.
//
// R1 lesson: VGPR=32 meant 1 outstanding load/wave -> latency-bound at 2.5 TB/s.
// R2: batch 8 independent float4 loads per compute group (8-deep MLP) and
// double the grid (TCHUNK 32->16, 2048 blocks) for wave pressure.

constexpr int Bc = 4;
constexpr int Tc = 8192;
constexpr int Fc = 1024;
constexpr int TCHUNK = 16;                 // t-rows per block
constexpr int CHUNKS = Tc / TCHUNK;        // 512
constexpr int NBLK = Bc * CHUNKS;          // 2048 blocks
constexpr int BATCH = 8;                   // loads in flight per wave

__global__ __launch_bounds__(256) void causal_conv1d_kernel(
    const float* __restrict__ x,
    const float* __restrict__ w,      // (K,1,F) -> w[k*F + f]
    const float* __restrict__ bias,   // (F,)
    float* __restrict__ out)
{
    const int f   = threadIdx.x * 4;  // feature group of 4
    const int bt  = blockIdx.x;
    const int b   = bt / CHUNKS;
    const int t0  = (bt % CHUNKS) * TCHUNK;

    const float4 w0 = *reinterpret_cast<const float4*>(w + 0 * Fc + f);
    const float4 w1 = *reinterpret_cast<const float4*>(w + 1 * Fc + f);
    const float4 w2 = *reinterpret_cast<const float4*>(w + 2 * Fc + f);
    const float4 w3 = *reinterpret_cast<const float4*>(w + 3 * Fc + f);
    const float4 bv = *reinterpret_cast<const float4*>(bias + f);

    const float* xp = x   + (size_t)b * Tc * Fc + f;
    float*       op = out + (size_t)b * Tc * Fc + f;

    // Sliding window: x[t-3], x[t-2], x[t-1]
    float4 xm3, xm2, xm1;
    if (t0 >= 3) {
        xm3 = *reinterpret_cast<const float4*>(xp + (size_t)(t0 - 3) * Fc);
        xm2 = *reinterpret_cast<const float4*>(xp + (size_t)(t0 - 2) * Fc);
        xm1 = *reinterpret_cast<const float4*>(xp + (size_t)(t0 - 1) * Fc);
    } else {
        xm3 = make_float4(0.f, 0.f, 0.f, 0.f);
        xm2 = make_float4(0.f, 0.f, 0.f, 0.f);
        xm1 = make_float4(0.f, 0.f, 0.f, 0.f);
    }

#pragma unroll
    for (int bb = 0; bb < TCHUNK / BATCH; ++bb) {
        // Issue BATCH independent loads first -> BATCH-deep MLP.
        float4 xc[BATCH];
#pragma unroll
        for (int i = 0; i < BATCH; ++i) {
            const int t = t0 + bb * BATCH + i;
            xc[i] = *reinterpret_cast<const float4*>(xp + (size_t)t * Fc);
        }
        // Then compute + store (VALU only, window carried in registers).
#pragma unroll
        for (int i = 0; i < BATCH; ++i) {
            const int t = t0 + bb * BATCH + i;
            float4 o;
            o.x = fmaf(w3.x, xc[i].x, fmaf(w2.x, xm1.x, fmaf(w1.x, xm2.x, fmaf(w0.x, xm3.x, bv.x))));
            o.y = fmaf(w3.y, xc[i].y, fmaf(w2.y, xm1.y, fmaf(w1.y, xm2.y, fmaf(w0.y, xm3.y, bv.y))));
            o.z = fmaf(w3.z, xc[i].z, fmaf(w2.z, xm1.z, fmaf(w1.z, xm2.z, fmaf(w0.z, xm3.z, bv.z))));
            o.w = fmaf(w3.w, xc[i].w, fmaf(w2.w, xm1.w, fmaf(w1.w, xm2.w, fmaf(w0.w, xm3.w, bv.w))));
            *reinterpret_cast<float4*>(op + (size_t)t * Fc) = o;
            xm3 = xm2; xm2 = xm1; xm1 = xc[i];
        }
    }
}

extern "C" void kernel_launch(void* const* d_in, const int* in_sizes, int n_in,
                              void* d_out, int out_size, void* d_ws, size_t ws_size,
                              hipStream_t stream) {
    const float* x    = (const float*)d_in[0];
    const float* w    = (const float*)d_in[1];
    const float* bias = (const float*)d_in[2];
    float* out        = (float*)d_out;

    causal_conv1d_kernel<<<NBLK, 256, 0, stream>>>(x, w, bias, out);
}